// Round 1
// 121.751 us; speedup vs baseline: 1.0139x; 1.0139x over previous
//
#include <hip/hip_runtime.h>

// DatasetProjector: per-example Conv1d(200ch->512-of-4096, k=3, pad=1) + bias + GELU,
// computing only dataset_id[b]'s 512-channel slice (8x algebraic cut).
//
// R6 = R5 + structural pipeline fix for the chunk loop:
//  - W no longer goes through LDS. prep writes a fragment-ordered layout
//    wf[oblk][tap][chunk][lane][8] so each A-fragment is ONE coalesced 1KB
//    global_load_dwordx4 direct to VGPRs (L2-resident: same-(d,m0) blocks walk
//    chunks in lockstep, ~1.5MB/XCD working set). Deletes 6/11 g2l16, 24.6KB LDS,
//    and 12/36 ds_read_b128 per wave per chunk.
//  - X stage is double-buffered (2 x 16.5KB = 33KB, still 2 blocks/CU): stage of
//    chunk c+1 issues inside chunk c's compute; ONE barrier per chunk whose
//    vmcnt(0) drain waits on ~1200-3700-cycle-old loads -> near-free.
//  - Per-tap W register prefetch (anxt[4], +16 VGPR) so in-order vmcnt waits
//    cover only ~1-tap-old loads.
//  - s_setprio(1) around each 4-MFMA cluster (T5; structure now role-diverse).
// X granule swizzle s = p ^ ((row>>1)&3) kept verbatim (R4 measured 0 conflicts).
// Note: ~78us/iter of total dur is harness d_ws/d_out re-poison fills (uncontrollable).

typedef unsigned short u16;
typedef __attribute__((ext_vector_type(8))) short bf16x8;
typedef __attribute__((ext_vector_type(4))) float f32x4;

#define CIN 200
#define CINP 224        // padded channels = 7 chunks of 32
#define T 1024
#define BATCH 32
#define MD 512
#define XT_ROWS 1026    // row t1 = t+1; rows 0 and 1025 are zeros
#define NCHUNK 7
#define XP_PITCH 202    // prep LDS pitch in u16 -> 101 dwords (odd => conflict-free)
#define TT 256          // t-tile
#define XROWS (TT + 2)  // 258 staged x rows (t0-1 .. t0+256)
#define XGRAN (XROWS * 4)     // 1032 16B granules = 16.5 KB per buffer
#define WOB 256               // 4096/16 o-blocks
#define WF_PER_OB (21 * 512)  // 3 taps x 7 chunks x 64 lanes x 8 u16 = 10752 u16/oblk

__device__ __forceinline__ u16 f2bf(float f) {
    unsigned u = __float_as_uint(f);
    u += 0x7FFFu + ((u >> 16) & 1u);   // RNE
    return (u16)(u >> 16);
}

// async global(16B) -> LDS, dest = wave-uniform base + lane*16
__device__ __forceinline__ void g2l16(void* lds, const void* g) {
    __builtin_amdgcn_global_load_lds(
        (const __attribute__((address_space(1))) unsigned int*)(uintptr_t)g,
        (__attribute__((address_space(3))) unsigned int*)(unsigned)(uintptr_t)lds,
        16, 0, 0);
}

// ---- fused prep: blocks [0,512) transpose x -> xt[b][t+1][224] bf16;
//      blocks [512, 512+256) transform W[o][i][k] -> wf fragment-ordered bf16 ----
__global__ __launch_bounds__(256) void prep(const float* __restrict__ x,
                                            const float* __restrict__ W,
                                            u16* __restrict__ xt,
                                            u16* __restrict__ wf) {
    __shared__ __align__(16) unsigned char smem[16 * 673 * 4];  // 43 KB, unioned
    const int tid = threadIdx.x;
    if (blockIdx.x < 512) {
        u16* tile = (u16*)smem;   // uses 64*202*2 = 25.9 KB of smem
        const int b  = blockIdx.x >> 4;
        const int bx = blockIdx.x & 15;
        const int t0 = bx * 64;
        const int tl = tid & 63;       // t within tile (lane -> coalesced x reads)
        const int w  = tid >> 6;
        const float* xb = x + (size_t)b * CIN * T + t0 + tl;
        for (int i = w; i < CIN; i += 4)                 // LDS row pitch 101 dwords (odd) -> conflict-free
            tile[tl * XP_PITCH + i] = f2bf(xb[(size_t)i * T]);
        __syncthreads();
        u16* xrow = xt + ((size_t)b * XT_ROWS + 1 + t0) * CINP;
        for (int it = 0; it < 16; ++it) {
            int r = it * 4 + w;
            if (tl < 56) {                               // 56 lanes x ushort4 = 224 ch
                ushort4 v = {0, 0, 0, 0};
                if (tl < 50) {                           // 50*4 = 200 valid channels
                    const u16* p = tile + r * XP_PITCH + tl * 4;
                    v.x = p[0]; v.y = p[1]; v.z = p[2]; v.w = p[3];
                }
                *(ushort4*)(xrow + (size_t)r * CINP + tl * 4) = v;
            }
        }
        if (bx == 0 && tid < 112)
            ((unsigned*)(xt + (size_t)b * XT_ROWS * CINP))[tid] = 0;          // t = -1 row
        if (bx == 15 && tid < 112)
            ((unsigned*)(xt + ((size_t)b * XT_ROWS + 1025) * CINP))[tid] = 0; // t = 1024 row
    } else {
        // W -> wf: one block per oblk (16 o-rows). Coalesced f32 load -> LDS ->
        // fully-coalesced u16 store in fragment order.
        float* wtile = (float*)smem;                     // [16][673] padded (673%32==1)
        const int ob = blockIdx.x - 512;
        const float* wp = W + (size_t)ob * 16 * 768;     // W rows o in [ob*16, ob*16+16)
        for (int j = tid; j < 16 * 672; j += 256) {      // only i<224 (first 672 f32/row) used
            int o = j / 672, r = j - o * 672;
            wtile[o * 673 + r] = wp[(size_t)o * 768 + r];
        }
        __syncthreads();
        u16* wo = wf + (size_t)ob * WF_PER_OB;
        for (int j = tid; j < WF_PER_OB; j += 256) {     // j = ((k*7+c)*64+lane)*8+e
            int e    = j & 7;
            int lane = (j >> 3) & 63;
            int kc   = j >> 9;                           // k*7 + c  (< 21)
            int cc   = kc % 7, k = kc / 7;
            int l = lane & 15, q = lane >> 4;
            int i = cc * 32 + q * 8 + e;                 // channel index
            // A-fragment semantics: lane (l,q) holds A[row=l][K=q*8+e] of o-row ob*16+l
            wo[j] = f2bf(wtile[l * 673 + i * 3 + k]);
        }
    }
}

// ---- main: per-example MFMA conv-GEMM, 128m x 256t per block, 512 blocks ----
__global__ __launch_bounds__(256, 2) void conv_mfma(const u16* __restrict__ xt,
                                                    const u16* __restrict__ wf,
                                                    const int* __restrict__ dsid,
                                                    const float* __restrict__ bias,
                                                    float* __restrict__ out) {
    __shared__ __align__(16) u16 xs[2 * XGRAN * 8];    // 33 KB: double-buffered X only

    const int tid = threadIdx.x;
    const int wave = tid >> 6, lane = tid & 63;
    const int l = lane & 15, quad = lane >> 4;
    const int wm  = (wave & 1) * 64;       // wave m offset (2 m-waves)
    const int wti = (wave >> 1) * 128;     // wave t offset (2 t-waves)

    // XCD-aware swizzle: ids {k, k+8, k+16, k+24} = the 4 m-blocks of one (b,t)
    // -> same (id % 8) -> same XCD -> xt slice fetched once per XCD.
    const int id = blockIdx.x;
    const int tb = (id >> 5) * 8 + (id & 7);   // 0..127 = (b, tloc)
    const int m0 = ((id >> 3) & 3) * 128;
    const int t0 = (tb & 3) * TT;
    const int b  = tb >> 2;
    const int d  = dsid[b];
    const int obase = d * MD + m0;

    f32x4 acc[4][8];
#pragma unroll
    for (int mi = 0; mi < 4; ++mi)
#pragma unroll
        for (int ti = 0; ti < 8; ++ti) acc[mi][ti] = (f32x4){0.f, 0.f, 0.f, 0.f};

    const u16* xbase = xt + ((size_t)b * XT_ROWS + t0) * CINP;  // row r -> t = t0+r-1
    // wave-uniform oblk base + per-lane 16B: each LOADW is one coalesced 1KB dwordx4
    const u16* wfw = wf + (size_t)((obase + wm) >> 4) * WF_PER_OB + lane * 8;

    // hoisted X staging addresses (chunk-invariant); chunk advance = +32 u16 = 64 B
    const u16* xsrc[5]; u16* xdst[5];
#pragma unroll
    for (int k = 0; k < 5; ++k) {
        int g = tid + k * 256;
        int r = g >> 2, p = g & 3, s = p ^ ((r >> 1) & 3);
        if (g < XGRAN) { xsrc[k] = xbase + (size_t)r * CINP + s * 8; xdst[k] = xs + (size_t)(g & ~63) * 8; }
        else           { xsrc[k] = xbase;                            xdst[k] = xs; }
    }

    auto stage = [&](int bsel, int c) {
        const int ic  = c * 32;
        const int off = bsel * (XGRAN * 8);
#pragma unroll
        for (int k = 0; k < 5; ++k)
            if (tid + k * 256 < XGRAN) g2l16(xdst[k] + off, xsrc[k] + ic);
    };
    auto loadw = [&](bf16x8* dst, int tap, int c) {
#pragma unroll
        for (int mi = 0; mi < 4; ++mi)
            dst[mi] = *(const bf16x8*)(wfw + (size_t)((mi * 21 + tap * 7 + c) << 9));
    };

    bf16x8 acur[4], anxt[4];
    stage(0, 0);
    loadw(acur, 0, 0);
    __syncthreads();   // drains vmcnt(0): buf0 + first A-frags ready

#pragma unroll
    for (int c = 0; c < NCHUNK; ++c) {
        const int bsel = c & 1;
        const u16* xb = xs + bsel * (XGRAN * 8);
#pragma unroll
        for (int tap = 0; tap < 3; ++tap) {
            // stage c+1 late (tap2 body): drained only at the chunk barrier,
            // ~1 tap (~1200cy) after issue, under MFMA.
            if (tap == 2 && c + 1 < NCHUNK) stage(bsel ^ 1, c + 1);
            // prefetch next tap's (or next chunk's tap0) A-fragments
            if (!(tap == 2 && c == NCHUNK - 1))
                loadw(anxt, (tap == 2 ? 0 : tap + 1), (tap == 2 ? c + 1 : c));
#pragma unroll
            for (int ti = 0; ti < 8; ++ti) {
                int row = wti + tap + ti * 16 + l;
                bf16x8 bv = *(const bf16x8*)(xb + ((size_t)row * 4 + (quad ^ ((row >> 1) & 3))) * 8);
                __builtin_amdgcn_s_setprio(1);
#pragma unroll
                for (int mi = 0; mi < 4; ++mi)
                    acc[mi][ti] = __builtin_amdgcn_mfma_f32_16x16x32_bf16(acur[mi], bv, acc[mi][ti], 0, 0, 0);
                __builtin_amdgcn_s_setprio(0);
            }
#pragma unroll
            for (int mi = 0; mi < 4; ++mi) acur[mi] = anxt[mi];   // renamed away by unroll
        }
        if (c + 1 < NCHUNK) __syncthreads();   // single barrier/chunk; drain is ~free
    }

    // epilogue: +bias, sigmoid-form tanh-GELU (exp2-folded, branchless), f32 store
#pragma unroll
    for (int mi = 0; mi < 4; ++mi) {
        float bvv[4];
#pragma unroll
        for (int r = 0; r < 4; ++r)
            bvv[r] = bias[obase + wm + mi * 16 + quad * 4 + r];
#pragma unroll
        for (int ti = 0; ti < 8; ++ti) {
            int t = t0 + wti + ti * 16 + l;
#pragma unroll
            for (int r = 0; r < 4; ++r) {
                int m = wm + mi * 16 + quad * 4 + r;
                float v = acc[mi][ti][r] + bvv[r];
                float p2 = v * v;
                // exp(-z), z = v*(1.59577 + 0.0713548 v^2), folded to exp2
                float z2 = v * fmaf(p2, -0.10295089f, -2.30243665f);
                float e = __builtin_amdgcn_exp2f(z2);
                float g = v * __builtin_amdgcn_rcpf(1.0f + e);   // v * sigmoid(z)
                out[((size_t)(b * MD + m0 + m)) * T + t] = g;
            }
        }
    }
}

extern "C" void kernel_launch(void* const* d_in, const int* in_sizes, int n_in,
                              void* d_out, int out_size, void* d_ws, size_t ws_size,
                              hipStream_t stream) {
    const float* x    = (const float*)d_in[0];
    const int*   dsid = (const int*)d_in[1];
    const float* W    = (const float*)d_in[2];
    const float* bias = (const float*)d_in[3];
    float* out = (float*)d_out;

    u16* xt = (u16*)d_ws;                                // 32*1026*224*2 = 14.7 MB
    u16* wf = xt + (size_t)BATCH * XT_ROWS * CINP;       // 256*21*512*2  =  5.5 MB

    prep<<<512 + WOB, 256, 0, stream>>>(x, W, xt, wf);
    conv_mfma<<<512, 256, 0, stream>>>(xt, wf, dsid, bias, out);
}